// Round 2
// baseline (852.467 us; speedup 1.0000x reference)
//
#include <hip/hip_runtime.h>

// Problem shapes (fixed by the reference):
//   kv_cache:     (2L, B, H, S, D) = (4, 8, 8, 4096, 128) fp32  -> 512 MiB
//   new_kv:       (L, 2, B, H, 1, D) = (2, 2, 8, 8, 1, 128) fp32 -> 128 KiB
//   position_ids: (B, 1) int32 (JAX demotes int64) -> 8 elems
//   out: kv_cache with row pos[b] of each (c, b, h) slice replaced by
//        new_kv[c, b, h, :], where c = 2*l + kv_type in 0..3 indexes both
//        the leading dim of out and the flattened (L,2) dims of new_kv.
//
// Strategy: ONE fused streaming-copy kernel (the hipMemcpyAsync D2D path
// only achieved ~1.26 TB/s aggregate; a plain 16B/lane grid-stride kernel
// should match the harness fill kernels at ~6.3 TB/s). The scatter is a
// predicated select on the decoded row index -- wave-uniformly false for
// all but 256 of 4.2M rows, fully hidden under HBM latency.
//
// NOTE: __builtin_nontemporal_* requires a native clang vector type, not
// HIP_vector_type<float,4> -- use ext_vector_type(4).

#define LL 2
#define BB 8
#define HH 8
#define SS 4096
#define DD 128

typedef float f32x4 __attribute__((ext_vector_type(4)));

// Total f32x4 elements in out: 2L*B*H*S*D / 4 = 2^25
#define TOTAL_F4 (2 * LL * BB * HH * SS * (DD / 4))

__global__ __launch_bounds__(256) void kv_copy_scatter(
    const f32x4* __restrict__ cache,
    const f32x4* __restrict__ new_kv,
    const int*   __restrict__ pos_ids,
    f32x4*       __restrict__ out)
{
    const int stride = gridDim.x * blockDim.x;          // 2048*256 = 2^19
    int i = blockIdx.x * blockDim.x + threadIdx.x;
    // Flat f32x4 index decode (all dims power-of-two):
    //   d4 = i & 31; s = (i>>5) & 4095; h = (i>>17) & 7; b = (i>>20) & 7; c = i>>23
    for (; i < TOTAL_F4; i += stride) {
        f32x4 v = __builtin_nontemporal_load(&cache[i]);
        int s = (i >> 5)  & (SS - 1);
        int b = (i >> 20) & (BB - 1);
        int pos = pos_ids[b];                // 32 B table, L1-resident
        if (s == pos) {                      // true for 256 rows / 4.2M
            int d4 = i & (DD / 4 - 1);
            int h  = (i >> 17) & (HH - 1);
            int c  = i >> 23;                // 0..3
            v = new_kv[((c * BB + b) * HH + h) * (DD / 4) + d4];
        }
        __builtin_nontemporal_store(v, &out[i]);
    }
}

extern "C" void kernel_launch(void* const* d_in, const int* in_sizes, int n_in,
                              void* d_out, int out_size, void* d_ws, size_t ws_size,
                              hipStream_t stream) {
    const f32x4* kv_cache = (const f32x4*)d_in[0];
    const f32x4* new_kv   = (const f32x4*)d_in[1];
    const int*   pos_ids  = (const int*)d_in[2];
    f32x4*       out      = (f32x4*)d_out;

    // 2048 blocks x 256 threads = 2^19 threads, 64 f32x4 per thread,
    // 8 blocks/CU on 256 CUs -- memory-bound sweet spot (Guideline 11).
    kv_copy_scatter<<<2048, 256, 0, stream>>>(kv_cache, new_kv, pos_ids, out);
}